// Round 9
// baseline (1685.048 us; speedup 1.0000x reference)
//
#include <hip/hip_runtime.h>
#include <cstddef>

#define BB 8
#define NN 1024
#define KK 20
#define CCAT 169
#define NT 16  // n-tiles of 64 in final fused GEMM

// ---------------- neg dist, tiled GEMM-style, norms fused in ----------------
// dist[b][n][m] = 2*sum_f x[f][n]*x[f][m] - ||x_n||^2 - ||x_m||^2
// single-buffer (r8 dbuf regressed: occupancy loss > pipeline gain)
template <int F>
__global__ __launch_bounds__(256) void dist_tile_kernel(
    const float* __restrict__ src, int bs, float* __restrict__ dist) {
  __shared__ float As[8][128];
  __shared__ float Bs[8][128];
  int b = blockIdx.z;
  int n0 = blockIdx.y * 128;
  int m0 = blockIdx.x * 128;
  int t = threadIdx.x;
  int tx = t & 15, ty = t >> 4;
  const float* p = src + (size_t)b * bs;

  float acc[8][8];
  float xn[8], xm[8];
#pragma unroll
  for (int i = 0; i < 8; ++i) {
    xn[i] = 0.f;
    xm[i] = 0.f;
#pragma unroll
    for (int j = 0; j < 8; ++j) acc[i][j] = 0.f;
  }

  int fr = t >> 5;
  int cc = (t & 31) << 2;
  constexpr int NCH = (F + 7) / 8;
#pragma unroll
  for (int k = 0; k < NCH; ++k) {
    int f = k * 8 + fr;
    float4 av = {0.f, 0.f, 0.f, 0.f}, bv = {0.f, 0.f, 0.f, 0.f};
    if (f < F) {
      av = *(const float4*)(p + (size_t)f * NN + n0 + cc);
      bv = *(const float4*)(p + (size_t)f * NN + m0 + cc);
    }
    __syncthreads();
    *(float4*)&As[fr][cc] = av;
    *(float4*)&Bs[fr][cc] = bv;
    __syncthreads();
#pragma unroll
    for (int f2 = 0; f2 < 8; ++f2) {
      float4 al = *(const float4*)&As[f2][ty << 2];
      float4 ah = *(const float4*)&As[f2][64 + (ty << 2)];
      float4 bl = *(const float4*)&Bs[f2][tx << 2];
      float4 bh = *(const float4*)&Bs[f2][64 + (tx << 2)];
      float a[8] = {al.x, al.y, al.z, al.w, ah.x, ah.y, ah.z, ah.w};
      float bb[8] = {bl.x, bl.y, bl.z, bl.w, bh.x, bh.y, bh.z, bh.w};
#pragma unroll
      for (int i = 0; i < 8; ++i) xn[i] += a[i] * a[i];
#pragma unroll
      for (int j = 0; j < 8; ++j) xm[j] += bb[j] * bb[j];
#pragma unroll
      for (int i = 0; i < 8; ++i)
#pragma unroll
        for (int j = 0; j < 8; ++j) acc[i][j] += a[i] * bb[j];
    }
  }

#pragma unroll
  for (int i = 0; i < 8; ++i) {
    int n = n0 + ((i < 4) ? ((ty << 2) + i) : (64 + (ty << 2) + i - 4));
    float* dr = dist + (((size_t)b * NN + n) << 10);
    float4 w0, w1;
    w0.x = 2.f * acc[i][0] - xn[i] - xm[0];
    w0.y = 2.f * acc[i][1] - xn[i] - xm[1];
    w0.z = 2.f * acc[i][2] - xn[i] - xm[2];
    w0.w = 2.f * acc[i][3] - xn[i] - xm[3];
    w1.x = 2.f * acc[i][4] - xn[i] - xm[4];
    w1.y = 2.f * acc[i][5] - xn[i] - xm[5];
    w1.z = 2.f * acc[i][6] - xn[i] - xm[6];
    w1.w = 2.f * acc[i][7] - xn[i] - xm[7];
    *(float4*)(dr + m0 + (tx << 2)) = w0;
    *(float4*)(dr + m0 + 64 + (tx << 2)) = w1;
  }
}

// ---------------- top-k (k=20) per row, one wave per row ----------------
__global__ void topk_kernel(const float* __restrict__ dist,
                            int* __restrict__ idx_out) {
  int wave = threadIdx.x >> 6;
  int lane = threadIdx.x & 63;
  int row = blockIdx.x * 4 + wave;
  const float* d = dist + ((size_t)row << 10);
  float v[16];
  int ix[16];
#pragma unroll
  for (int s = 0; s < 16; ++s) {
    int m = lane + s * 64;
    v[s] = d[m];
    ix[s] = m;
  }
  int* out = idx_out + row * KK;
  for (int r = 0; r < KK; ++r) {
    float bv = -__builtin_inff();
    int bi = NN;
#pragma unroll
    for (int s = 0; s < 16; ++s) {
      if (v[s] > bv || (v[s] == bv && ix[s] < bi)) { bv = v[s]; bi = ix[s]; }
    }
    for (int off = 32; off > 0; off >>= 1) {
      float ov = __shfl_xor(bv, off, 64);
      int oi = __shfl_xor(bi, off, 64);
      if (ov > bv || (ov == bv && oi < bi)) { bv = ov; bi = oi; }
    }
    if (lane == 0) out[r] = bi;
#pragma unroll
    for (int s = 0; s < 16; ++s)
      if (ix[s] == bi) v[s] = -__builtin_inff();
  }
}

// ---------------- fused transform + edge combine + mean over k ----------------
template <int D>
__global__ __launch_bounds__(256) void edge_fused_kernel(
    const float* __restrict__ src, int bs, int Co,
    const float* __restrict__ Wf, const float* __restrict__ Wd,
    const int* __restrict__ idx, int ooff, float* __restrict__ xcat) {
  __shared__ float2 Ulds[3 * NN];  // 24 KB {Uf,Ud}
  __shared__ float2 Vlds[3 * NN];  // 24 KB {Vf,Vd}
  __shared__ float4 Wlds[D > 0 ? D : 1];  // {wfa, wfb, wda, wdb}
  int bo = blockIdx.x;
  int b = bo / Co, o = bo % Co;
  int t = threadIdx.x;

  if (t < D) {
    float wfa = Wf[o * 2 * D + t];
    float wfb = Wf[o * 2 * D + D + t] - wfa;
    float wda = Wd[o * 2 * D + t];
    float wdb = Wd[o * 2 * D + D + t] - wda;
    Wlds[t] = make_float4(wfa, wfb, wda, wdb);
  }
  __syncthreads();

  const float* sb = src + (size_t)b * bs;
#pragma unroll
  for (int r = 0; r < 3; ++r) {
    int g = t + 256 * r;
    float4 uf = {0.f, 0.f, 0.f, 0.f}, vf = {0.f, 0.f, 0.f, 0.f};
    float4 ud = {0.f, 0.f, 0.f, 0.f}, vd = {0.f, 0.f, 0.f, 0.f};
    for (int i = 0; i < D; ++i) {
      float4 s = *(const float4*)(sb + (size_t)i * 3 * NN + (g << 2));
      float4 w = Wlds[i];
      uf.x += w.x * s.x; uf.y += w.x * s.y; uf.z += w.x * s.z; uf.w += w.x * s.w;
      vf.x += w.y * s.x; vf.y += w.y * s.y; vf.z += w.y * s.z; vf.w += w.y * s.w;
      ud.x += w.z * s.x; ud.y += w.z * s.y; ud.z += w.z * s.z; ud.w += w.z * s.w;
      vd.x += w.w * s.x; vd.y += w.w * s.y; vd.z += w.w * s.z; vd.w += w.w * s.w;
    }
    *(float4*)&Ulds[(g << 2) + 0] = make_float4(uf.x, ud.x, uf.y, ud.y);
    *(float4*)&Ulds[(g << 2) + 2] = make_float4(uf.z, ud.z, uf.w, ud.w);
    *(float4*)&Vlds[(g << 2) + 0] = make_float4(vf.x, vd.x, vf.y, vd.y);
    *(float4*)&Vlds[(g << 2) + 2] = make_float4(vf.z, vd.z, vf.w, vd.w);
  }
  __syncthreads();

  const float inv_k = 1.f / KK;
#pragma unroll
  for (int rep = 0; rep < 4; ++rep) {
    int n = rep * 256 + t;
    float2 v0 = Vlds[n];
    float2 v1 = Vlds[NN + n];
    float2 v2 = Vlds[2 * NN + n];
    const int4* ip = (const int4*)(idx + (b * NN + n) * KK);
    float a0 = 0.f, a1 = 0.f, a2 = 0.f;
#pragma unroll
    for (int q = 0; q < 5; ++q) {
      int4 iv = ip[q];
      int nbs[4] = {iv.x, iv.y, iv.z, iv.w};
#pragma unroll
      for (int jj = 0; jj < 4; ++jj) {
        int nb = nbs[jj];
        float2 u0 = Ulds[nb];
        float2 u1 = Ulds[NN + nb];
        float2 u2 = Ulds[2 * NN + nb];
        float pf0 = u0.x + v0.x, pd0 = u0.y + v0.y;
        float pf1 = u1.x + v1.x, pd1 = u1.y + v1.y;
        float pf2 = u2.x + v2.x, pd2 = u2.y + v2.y;
        float dot = pf0 * pd0 + pf1 * pd1 + pf2 * pd2;
        float dsq = pd0 * pd0 + pd1 * pd1 + pd2 * pd2;
        float g = (dot >= 0.f) ? 0.f : 0.8f * dot / (dsq + 1e-6f);
        a0 += pf0 - g * pd0;
        a1 += pf1 - g * pd1;
        a2 += pf2 - g * pd2;
      }
    }
    size_t ob = (size_t)b * CCAT * 3 * NN + (size_t)(ooff + o) * 3 * NN + n;
    xcat[ob] = a0 * inv_k;
    xcat[ob + NN] = a1 * inv_k;
    xcat[ob + 2 * NN] = a2 * inv_k;
  }
}

// ---------------- fused final GEMM + dvec + VN-leakyrelu + partial n-sum ----------------
// Single-buffer (dbuf regressed), o-tile 32 / n-tile 64 -> 1408 blocks for TLP.
// Micro-tile per thread: 2 o x 4 n x 3 c.
__global__ __launch_bounds__(256) void final_fused_kernel(
    const float* __restrict__ xcat, const float* __restrict__ Wf4,
    const float* __restrict__ Wd4, float* __restrict__ part) {
  __shared__ float Ws[16][32];
  __shared__ float Xs[3][16][64];
  __shared__ float Wds[16];
  int b = blockIdx.z;
  int o0 = blockIdx.y * 32;
  int n0 = blockIdx.x * 64;
  int t = threadIdx.x;
  int tx = t & 15, ty = t >> 4;
  constexpr int NCH = (CCAT + 15) / 16;  // 11

  float acc[3][2][4];  // [c][o_i][n_j]
  float dv[3][4];      // [c][n_j]
#pragma unroll
  for (int c = 0; c < 3; ++c) {
#pragma unroll
    for (int i = 0; i < 2; ++i)
#pragma unroll
      for (int j = 0; j < 4; ++j) acc[c][i][j] = 0.f;
#pragma unroll
    for (int j = 0; j < 4; ++j) dv[c][j] = 0.f;
  }

  const float* xb = xcat + (size_t)b * CCAT * 3 * NN;
  for (int f0 = 0; f0 < CCAT; f0 += 16) {
    int f = f0 + ty;
    float4 xv[3];
#pragma unroll
    for (int c = 0; c < 3; ++c) {
      xv[c] = make_float4(0.f, 0.f, 0.f, 0.f);
      if (f < CCAT)
        xv[c] = *(const float4*)(xb + ((size_t)f * 3 + c) * NN + n0 + (tx << 2));
    }
    float wv[2];
#pragma unroll
    for (int q = 0; q < 2; ++q) {
      int o = o0 + (tx << 1) + q;
      wv[q] = (o < 341 && f < CCAT) ? Wf4[o * CCAT + f] : 0.f;
    }
    float wdv = 0.f;
    if (t < 16 && f0 + t < CCAT) wdv = Wd4[f0 + t];
    __syncthreads();
#pragma unroll
    for (int c = 0; c < 3; ++c) *(float4*)&Xs[c][ty][tx << 2] = xv[c];
    *(float2*)&Ws[ty][tx << 1] = make_float2(wv[0], wv[1]);
    if (t < 16) Wds[t] = wdv;
    __syncthreads();
#pragma unroll
    for (int f2 = 0; f2 < 16; ++f2) {
      float2 w = *(const float2*)&Ws[f2][ty << 1];
      float wa[2] = {w.x, w.y};
      float wd = Wds[f2];
#pragma unroll
      for (int c = 0; c < 3; ++c) {
        float4 x = *(const float4*)&Xs[c][f2][tx << 2];
        float xa[4] = {x.x, x.y, x.z, x.w};
#pragma unroll
        for (int j = 0; j < 4; ++j) dv[c][j] += wd * xa[j];
#pragma unroll
        for (int i = 0; i < 2; ++i)
#pragma unroll
          for (int j = 0; j < 4; ++j) acc[c][i][j] += wa[i] * xa[j];
      }
    }
  }

  float s[3][2];
#pragma unroll
  for (int c = 0; c < 3; ++c)
#pragma unroll
    for (int i = 0; i < 2; ++i) s[c][i] = 0.f;
#pragma unroll
  for (int i = 0; i < 2; ++i) {
#pragma unroll
    for (int j = 0; j < 4; ++j) {
      float d0 = dv[0][j], d1 = dv[1][j], d2 = dv[2][j];
      float p0 = acc[0][i][j], p1 = acc[1][i][j], p2 = acc[2][i][j];
      float dot = p0 * d0 + p1 * d1 + p2 * d2;
      float dsq = d0 * d0 + d1 * d1 + d2 * d2;
      float g = (dot >= 0.f) ? 0.f : 0.8f * dot / (dsq + 1e-6f);
      s[0][i] += p0 - g * d0;
      s[1][i] += p1 - g * d1;
      s[2][i] += p2 - g * d2;
    }
  }

  // reduce across tx (lane bits [3:0] within each wave)
#pragma unroll
  for (int off = 1; off < 16; off <<= 1) {
#pragma unroll
    for (int c = 0; c < 3; ++c)
#pragma unroll
      for (int i = 0; i < 2; ++i) s[c][i] += __shfl_xor(s[c][i], off, 64);
  }
  if (tx == 0) {
#pragma unroll
    for (int i = 0; i < 2; ++i) {
      int o = o0 + (ty << 1) + i;
      if (o < 341) {
#pragma unroll
        for (int c = 0; c < 3; ++c)
          part[(((size_t)b * 341 + o) * 3 + c) * NT + blockIdx.x] = s[c][i];
      }
    }
  }
}

__global__ void final_reduce_kernel(const float* __restrict__ part,
                                    float* __restrict__ out) {
  int t = blockIdx.x * 256 + threadIdx.x;
  if (t >= BB * 341 * 3) return;
  const float* p = part + (size_t)t * NT;
  float s = 0.f;
#pragma unroll
  for (int nt = 0; nt < NT; ++nt) s += p[nt];
  out[t] = s * (1.f / 1024.f);
}

extern "C" void kernel_launch(void* const* d_in, const int* in_sizes, int n_in,
                              void* d_out, int out_size, void* d_ws,
                              size_t ws_size, hipStream_t stream) {
  (void)in_sizes; (void)n_in; (void)out_size; (void)ws_size;
  const float* x = (const float*)d_in[0];
  const float* Wf[5] = {(const float*)d_in[1], (const float*)d_in[3],
                        (const float*)d_in[5], (const float*)d_in[7],
                        (const float*)d_in[9]};
  const float* Wd[5] = {(const float*)d_in[2], (const float*)d_in[4],
                        (const float*)d_in[6], (const float*)d_in[8],
                        (const float*)d_in[10]};

  float* ws = (float*)d_ws;
  float* dist = ws;
  float* part = ws;  // dist region dead once final_fused runs
  size_t off = (size_t)BB * NN * NN;
  int* idx = (int*)(ws + off);
  off += (size_t)BB * NN * KK;
  float* xcat = ws + off;

  const int inoff[4] = {0, 0, 21, 42};
  const int ooff[4] = {0, 21, 42, 84};
  const int CoL[4] = {21, 21, 42, 85};

  for (int l = 0; l < 4; ++l) {
    const float* src = (l == 0) ? x : (xcat + (size_t)inoff[l] * 3 * NN);
    int bs = (l == 0) ? 3 * NN : CCAT * 3 * NN;
    int Co = CoL[l];

    switch (l) {
      case 0:
        dist_tile_kernel<3><<<dim3(8, 8, BB), 256, 0, stream>>>(src, bs, dist);
        break;
      case 1:
      case 2:
        dist_tile_kernel<63><<<dim3(8, 8, BB), 256, 0, stream>>>(src, bs, dist);
        break;
      case 3:
        dist_tile_kernel<126><<<dim3(8, 8, BB), 256, 0, stream>>>(src, bs, dist);
        break;
    }
    topk_kernel<<<(BB * NN) / 4, 256, 0, stream>>>(dist, idx);
    switch (l) {
      case 0:
        edge_fused_kernel<1><<<BB * Co, 256, 0, stream>>>(
            src, bs, Co, Wf[l], Wd[l], idx, ooff[l], xcat);
        break;
      case 1:
      case 2:
        edge_fused_kernel<21><<<BB * Co, 256, 0, stream>>>(
            src, bs, Co, Wf[l], Wd[l], idx, ooff[l], xcat);
        break;
      case 3:
        edge_fused_kernel<42><<<BB * Co, 256, 0, stream>>>(
            src, bs, Co, Wf[l], Wd[l], idx, ooff[l], xcat);
        break;
    }
  }

  final_fused_kernel<<<dim3(NT, 11, BB), 256, 0, stream>>>(xcat, Wf[4], Wd[4],
                                                           part);
  final_reduce_kernel<<<(BB * 341 * 3 + 255) / 256, 256, 0, stream>>>(
      part, (float*)d_out);
}

// Round 10
// 609.657 us; speedup vs baseline: 2.7639x; 2.7639x over previous
//
#include <hip/hip_runtime.h>
#include <cstddef>

#define BB 8
#define NN 1024
#define KK 20
#define CCAT 169
#define NT 16  // n-tiles of 64 in final fused GEMM

// ---------------- neg dist, tiled GEMM-style, norms fused in ----------------
// dist[b][n][m] = 2*sum_f x[f][n]*x[f][m] - ||x_n||^2 - ||x_m||^2
// NOTE: chunk loop intentionally NOT unrolled — full unroll (r9) spilled to
// scratch (VGPR 256, 1 GB WRITE_SIZE, 671 us). Runtime-trip loop keeps ~110 VGPR.
template <int F>
__global__ __launch_bounds__(256) void dist_tile_kernel(
    const float* __restrict__ src, int bs, float* __restrict__ dist) {
  __shared__ float As[8][128];
  __shared__ float Bs[8][128];
  int b = blockIdx.z;
  int n0 = blockIdx.y * 128;
  int m0 = blockIdx.x * 128;
  int t = threadIdx.x;
  int tx = t & 15, ty = t >> 4;
  const float* p = src + (size_t)b * bs;

  float acc[8][8];
  float xn[8], xm[8];
#pragma unroll
  for (int i = 0; i < 8; ++i) {
    xn[i] = 0.f;
    xm[i] = 0.f;
#pragma unroll
    for (int j = 0; j < 8; ++j) acc[i][j] = 0.f;
  }

  int fr = t >> 5;
  int cc = (t & 31) << 2;
  const int NCH = (F + 7) / 8;
#pragma unroll 1
  for (int k = 0; k < NCH; ++k) {
    int f = k * 8 + fr;
    float4 av = {0.f, 0.f, 0.f, 0.f}, bv = {0.f, 0.f, 0.f, 0.f};
    if (f < F) {
      av = *(const float4*)(p + (size_t)f * NN + n0 + cc);
      bv = *(const float4*)(p + (size_t)f * NN + m0 + cc);
    }
    __syncthreads();
    *(float4*)&As[fr][cc] = av;
    *(float4*)&Bs[fr][cc] = bv;
    __syncthreads();
#pragma unroll
    for (int f2 = 0; f2 < 8; ++f2) {
      float4 al = *(const float4*)&As[f2][ty << 2];
      float4 ah = *(const float4*)&As[f2][64 + (ty << 2)];
      float4 bl = *(const float4*)&Bs[f2][tx << 2];
      float4 bh = *(const float4*)&Bs[f2][64 + (tx << 2)];
      float a[8] = {al.x, al.y, al.z, al.w, ah.x, ah.y, ah.z, ah.w};
      float bb[8] = {bl.x, bl.y, bl.z, bl.w, bh.x, bh.y, bh.z, bh.w};
#pragma unroll
      for (int i = 0; i < 8; ++i) xn[i] += a[i] * a[i];
#pragma unroll
      for (int j = 0; j < 8; ++j) xm[j] += bb[j] * bb[j];
#pragma unroll
      for (int i = 0; i < 8; ++i)
#pragma unroll
        for (int j = 0; j < 8; ++j) acc[i][j] += a[i] * bb[j];
    }
  }

#pragma unroll
  for (int i = 0; i < 8; ++i) {
    int n = n0 + ((i < 4) ? ((ty << 2) + i) : (64 + (ty << 2) + i - 4));
    float* dr = dist + (((size_t)b * NN + n) << 10);
    float4 w0, w1;
    w0.x = 2.f * acc[i][0] - xn[i] - xm[0];
    w0.y = 2.f * acc[i][1] - xn[i] - xm[1];
    w0.z = 2.f * acc[i][2] - xn[i] - xm[2];
    w0.w = 2.f * acc[i][3] - xn[i] - xm[3];
    w1.x = 2.f * acc[i][4] - xn[i] - xm[4];
    w1.y = 2.f * acc[i][5] - xn[i] - xm[5];
    w1.z = 2.f * acc[i][6] - xn[i] - xm[6];
    w1.w = 2.f * acc[i][7] - xn[i] - xm[7];
    *(float4*)(dr + m0 + (tx << 2)) = w0;
    *(float4*)(dr + m0 + 64 + (tx << 2)) = w1;
  }
}

// ---------------- top-k (k=20) per row, one wave per row ----------------
__global__ void topk_kernel(const float* __restrict__ dist,
                            int* __restrict__ idx_out) {
  int wave = threadIdx.x >> 6;
  int lane = threadIdx.x & 63;
  int row = blockIdx.x * 4 + wave;
  const float* d = dist + ((size_t)row << 10);
  float v[16];
  int ix[16];
#pragma unroll
  for (int s = 0; s < 16; ++s) {
    int m = lane + s * 64;
    v[s] = d[m];
    ix[s] = m;
  }
  int* out = idx_out + row * KK;
  for (int r = 0; r < KK; ++r) {
    float bv = -__builtin_inff();
    int bi = NN;
#pragma unroll
    for (int s = 0; s < 16; ++s) {
      if (v[s] > bv || (v[s] == bv && ix[s] < bi)) { bv = v[s]; bi = ix[s]; }
    }
    for (int off = 32; off > 0; off >>= 1) {
      float ov = __shfl_xor(bv, off, 64);
      int oi = __shfl_xor(bi, off, 64);
      if (ov > bv || (ov == bv && oi < bi)) { bv = ov; bi = oi; }
    }
    if (lane == 0) out[r] = bi;
#pragma unroll
    for (int s = 0; s < 16; ++s)
      if (ix[s] == bi) v[s] = -__builtin_inff();
  }
}

// ---------------- fused transform + edge combine + mean over k ----------------
template <int D>
__global__ __launch_bounds__(256) void edge_fused_kernel(
    const float* __restrict__ src, int bs, int Co,
    const float* __restrict__ Wf, const float* __restrict__ Wd,
    const int* __restrict__ idx, int ooff, float* __restrict__ xcat) {
  __shared__ float2 Ulds[3 * NN];  // 24 KB {Uf,Ud}
  __shared__ float2 Vlds[3 * NN];  // 24 KB {Vf,Vd}
  __shared__ float4 Wlds[D > 0 ? D : 1];  // {wfa, wfb, wda, wdb}
  int bo = blockIdx.x;
  int b = bo / Co, o = bo % Co;
  int t = threadIdx.x;

  if (t < D) {
    float wfa = Wf[o * 2 * D + t];
    float wfb = Wf[o * 2 * D + D + t] - wfa;
    float wda = Wd[o * 2 * D + t];
    float wdb = Wd[o * 2 * D + D + t] - wda;
    Wlds[t] = make_float4(wfa, wfb, wda, wdb);
  }
  __syncthreads();

  const float* sb = src + (size_t)b * bs;
#pragma unroll
  for (int r = 0; r < 3; ++r) {
    int g = t + 256 * r;
    float4 uf = {0.f, 0.f, 0.f, 0.f}, vf = {0.f, 0.f, 0.f, 0.f};
    float4 ud = {0.f, 0.f, 0.f, 0.f}, vd = {0.f, 0.f, 0.f, 0.f};
    for (int i = 0; i < D; ++i) {
      float4 s = *(const float4*)(sb + (size_t)i * 3 * NN + (g << 2));
      float4 w = Wlds[i];
      uf.x += w.x * s.x; uf.y += w.x * s.y; uf.z += w.x * s.z; uf.w += w.x * s.w;
      vf.x += w.y * s.x; vf.y += w.y * s.y; vf.z += w.y * s.z; vf.w += w.y * s.w;
      ud.x += w.z * s.x; ud.y += w.z * s.y; ud.z += w.z * s.z; ud.w += w.z * s.w;
      vd.x += w.w * s.x; vd.y += w.w * s.y; vd.z += w.w * s.z; vd.w += w.w * s.w;
    }
    *(float4*)&Ulds[(g << 2) + 0] = make_float4(uf.x, ud.x, uf.y, ud.y);
    *(float4*)&Ulds[(g << 2) + 2] = make_float4(uf.z, ud.z, uf.w, ud.w);
    *(float4*)&Vlds[(g << 2) + 0] = make_float4(vf.x, vd.x, vf.y, vd.y);
    *(float4*)&Vlds[(g << 2) + 2] = make_float4(vf.z, vd.z, vf.w, vd.w);
  }
  __syncthreads();

  const float inv_k = 1.f / KK;
#pragma unroll
  for (int rep = 0; rep < 4; ++rep) {
    int n = rep * 256 + t;
    float2 v0 = Vlds[n];
    float2 v1 = Vlds[NN + n];
    float2 v2 = Vlds[2 * NN + n];
    const int4* ip = (const int4*)(idx + (b * NN + n) * KK);
    float a0 = 0.f, a1 = 0.f, a2 = 0.f;
#pragma unroll
    for (int q = 0; q < 5; ++q) {
      int4 iv = ip[q];
      int nbs[4] = {iv.x, iv.y, iv.z, iv.w};
#pragma unroll
      for (int jj = 0; jj < 4; ++jj) {
        int nb = nbs[jj];
        float2 u0 = Ulds[nb];
        float2 u1 = Ulds[NN + nb];
        float2 u2 = Ulds[2 * NN + nb];
        float pf0 = u0.x + v0.x, pd0 = u0.y + v0.y;
        float pf1 = u1.x + v1.x, pd1 = u1.y + v1.y;
        float pf2 = u2.x + v2.x, pd2 = u2.y + v2.y;
        float dot = pf0 * pd0 + pf1 * pd1 + pf2 * pd2;
        float dsq = pd0 * pd0 + pd1 * pd1 + pd2 * pd2;
        float g = (dot >= 0.f) ? 0.f : 0.8f * dot / (dsq + 1e-6f);
        a0 += pf0 - g * pd0;
        a1 += pf1 - g * pd1;
        a2 += pf2 - g * pd2;
      }
    }
    size_t ob = (size_t)b * CCAT * 3 * NN + (size_t)(ooff + o) * 3 * NN + n;
    xcat[ob] = a0 * inv_k;
    xcat[ob + NN] = a1 * inv_k;
    xcat[ob + 2 * NN] = a2 * inv_k;
  }
}

// ---------------- fused final GEMM + dvec + VN-leakyrelu + partial n-sum ----------------
// Single-buffer, o-tile 32 / n-tile 64 -> 1408 blocks for TLP.
// Micro-tile per thread: 2 o x 4 n x 3 c.
__global__ __launch_bounds__(256) void final_fused_kernel(
    const float* __restrict__ xcat, const float* __restrict__ Wf4,
    const float* __restrict__ Wd4, float* __restrict__ part) {
  __shared__ float Ws[16][32];
  __shared__ float Xs[3][16][64];
  __shared__ float Wds[16];
  int b = blockIdx.z;
  int o0 = blockIdx.y * 32;
  int n0 = blockIdx.x * 64;
  int t = threadIdx.x;
  int tx = t & 15, ty = t >> 4;

  float acc[3][2][4];  // [c][o_i][n_j]
  float dv[3][4];      // [c][n_j]
#pragma unroll
  for (int c = 0; c < 3; ++c) {
#pragma unroll
    for (int i = 0; i < 2; ++i)
#pragma unroll
      for (int j = 0; j < 4; ++j) acc[c][i][j] = 0.f;
#pragma unroll
    for (int j = 0; j < 4; ++j) dv[c][j] = 0.f;
  }

  const float* xb = xcat + (size_t)b * CCAT * 3 * NN;
#pragma unroll 1
  for (int f0 = 0; f0 < CCAT; f0 += 16) {
    int f = f0 + ty;
    float4 xv[3];
#pragma unroll
    for (int c = 0; c < 3; ++c) {
      xv[c] = make_float4(0.f, 0.f, 0.f, 0.f);
      if (f < CCAT)
        xv[c] = *(const float4*)(xb + ((size_t)f * 3 + c) * NN + n0 + (tx << 2));
    }
    float wv[2];
#pragma unroll
    for (int q = 0; q < 2; ++q) {
      int o = o0 + (tx << 1) + q;
      wv[q] = (o < 341 && f < CCAT) ? Wf4[o * CCAT + f] : 0.f;
    }
    float wdv = 0.f;
    if (t < 16 && f0 + t < CCAT) wdv = Wd4[f0 + t];
    __syncthreads();
#pragma unroll
    for (int c = 0; c < 3; ++c) *(float4*)&Xs[c][ty][tx << 2] = xv[c];
    *(float2*)&Ws[ty][tx << 1] = make_float2(wv[0], wv[1]);
    if (t < 16) Wds[t] = wdv;
    __syncthreads();
#pragma unroll
    for (int f2 = 0; f2 < 16; ++f2) {
      float2 w = *(const float2*)&Ws[f2][ty << 1];
      float wa[2] = {w.x, w.y};
      float wd = Wds[f2];
#pragma unroll
      for (int c = 0; c < 3; ++c) {
        float4 x = *(const float4*)&Xs[c][f2][tx << 2];
        float xa[4] = {x.x, x.y, x.z, x.w};
#pragma unroll
        for (int j = 0; j < 4; ++j) dv[c][j] += wd * xa[j];
#pragma unroll
        for (int i = 0; i < 2; ++i)
#pragma unroll
          for (int j = 0; j < 4; ++j) acc[c][i][j] += wa[i] * xa[j];
      }
    }
  }

  float s[3][2];
#pragma unroll
  for (int c = 0; c < 3; ++c)
#pragma unroll
    for (int i = 0; i < 2; ++i) s[c][i] = 0.f;
#pragma unroll
  for (int i = 0; i < 2; ++i) {
#pragma unroll
    for (int j = 0; j < 4; ++j) {
      float d0 = dv[0][j], d1 = dv[1][j], d2 = dv[2][j];
      float p0 = acc[0][i][j], p1 = acc[1][i][j], p2 = acc[2][i][j];
      float dot = p0 * d0 + p1 * d1 + p2 * d2;
      float dsq = d0 * d0 + d1 * d1 + d2 * d2;
      float g = (dot >= 0.f) ? 0.f : 0.8f * dot / (dsq + 1e-6f);
      s[0][i] += p0 - g * d0;
      s[1][i] += p1 - g * d1;
      s[2][i] += p2 - g * d2;
    }
  }

  // reduce across tx (lane bits [3:0] within each wave)
#pragma unroll
  for (int off = 1; off < 16; off <<= 1) {
#pragma unroll
    for (int c = 0; c < 3; ++c)
#pragma unroll
      for (int i = 0; i < 2; ++i) s[c][i] += __shfl_xor(s[c][i], off, 64);
  }
  if (tx == 0) {
#pragma unroll
    for (int i = 0; i < 2; ++i) {
      int o = o0 + (ty << 1) + i;
      if (o < 341) {
#pragma unroll
        for (int c = 0; c < 3; ++c)
          part[(((size_t)b * 341 + o) * 3 + c) * NT + blockIdx.x] = s[c][i];
      }
    }
  }
}

__global__ void final_reduce_kernel(const float* __restrict__ part,
                                    float* __restrict__ out) {
  int t = blockIdx.x * 256 + threadIdx.x;
  if (t >= BB * 341 * 3) return;
  const float* p = part + (size_t)t * NT;
  float s = 0.f;
#pragma unroll
  for (int nt = 0; nt < NT; ++nt) s += p[nt];
  out[t] = s * (1.f / 1024.f);
}

extern "C" void kernel_launch(void* const* d_in, const int* in_sizes, int n_in,
                              void* d_out, int out_size, void* d_ws,
                              size_t ws_size, hipStream_t stream) {
  (void)in_sizes; (void)n_in; (void)out_size; (void)ws_size;
  const float* x = (const float*)d_in[0];
  const float* Wf[5] = {(const float*)d_in[1], (const float*)d_in[3],
                        (const float*)d_in[5], (const float*)d_in[7],
                        (const float*)d_in[9]};
  const float* Wd[5] = {(const float*)d_in[2], (const float*)d_in[4],
                        (const float*)d_in[6], (const float*)d_in[8],
                        (const float*)d_in[10]};

  float* ws = (float*)d_ws;
  float* dist = ws;
  float* part = ws;  // dist region dead once final_fused runs
  size_t off = (size_t)BB * NN * NN;
  int* idx = (int*)(ws + off);
  off += (size_t)BB * NN * KK;
  float* xcat = ws + off;

  const int inoff[4] = {0, 0, 21, 42};
  const int ooff[4] = {0, 21, 42, 84};
  const int CoL[4] = {21, 21, 42, 85};

  for (int l = 0; l < 4; ++l) {
    const float* src = (l == 0) ? x : (xcat + (size_t)inoff[l] * 3 * NN);
    int bs = (l == 0) ? 3 * NN : CCAT * 3 * NN;
    int Co = CoL[l];

    switch (l) {
      case 0:
        dist_tile_kernel<3><<<dim3(8, 8, BB), 256, 0, stream>>>(src, bs, dist);
        break;
      case 1:
      case 2:
        dist_tile_kernel<63><<<dim3(8, 8, BB), 256, 0, stream>>>(src, bs, dist);
        break;
      case 3:
        dist_tile_kernel<126><<<dim3(8, 8, BB), 256, 0, stream>>>(src, bs, dist);
        break;
    }
    topk_kernel<<<(BB * NN) / 4, 256, 0, stream>>>(dist, idx);
    switch (l) {
      case 0:
        edge_fused_kernel<1><<<BB * Co, 256, 0, stream>>>(
            src, bs, Co, Wf[l], Wd[l], idx, ooff[l], xcat);
        break;
      case 1:
      case 2:
        edge_fused_kernel<21><<<BB * Co, 256, 0, stream>>>(
            src, bs, Co, Wf[l], Wd[l], idx, ooff[l], xcat);
        break;
      case 3:
        edge_fused_kernel<42><<<BB * Co, 256, 0, stream>>>(
            src, bs, Co, Wf[l], Wd[l], idx, ooff[l], xcat);
        break;
    }
  }

  final_fused_kernel<<<dim3(NT, 11, BB), 256, 0, stream>>>(xcat, Wf[4], Wd[4],
                                                           part);
  final_reduce_kernel<<<(BB * 341 * 3 + 255) / 256, 256, 0, stream>>>(
      part, (float*)d_out);
}